// Round 2
// baseline (1797.721 us; speedup 1.0000x reference)
//
#include <hip/hip_runtime.h>
#include <hip/hip_bf16.h>
#include <math.h>

// Problem constants
#define BATCH 64
#define LDIM  256
#define HDIM  1024
#define DDIM  1024
#define BAND  16
#define MNZ   33          // 2*BAND+1
#define NN    (DDIM*MNZ)  // 33792
#define RTILE 64          // k3 rows per block
#define LSTR  34          // k3 LDS row stride (pad 33->34)

// DIAGNOSTIC repeats (idempotent; per-kernel dispatch becomes long enough to
// clear the ~167us fill cutoff and appear in top-5 WITH counters).
#define R2 12
#define R3 6

typedef float  v4f    __attribute__((ext_vector_type(4)));
typedef float  f32x4  __attribute__((ext_vector_type(4)));
typedef short  bf16x8 __attribute__((ext_vector_type(8)));

static __device__ __forceinline__ unsigned short f2bf(float x) {
    union { float f; unsigned int u; } a; a.f = x;
    unsigned int r = a.u + 0x7fffu + ((a.u >> 16) & 1u);
    return (unsigned short)(r >> 16);
}

// ---------------------------------------------------------------------------
// K1: h = gelu(z @ W1 + b1) -> bf16, row-major hb[b][k]   (unchanged; ~4 us)
// ---------------------------------------------------------------------------
__global__ __launch_bounds__(256) void k1_h(const float* __restrict__ z,
                                            const float* __restrict__ W1,
                                            const float* __restrict__ b1,
                                            unsigned short* __restrict__ hb) {
    __shared__ float zs[LDIM];
    const int t = threadIdx.x;
    const int b = blockIdx.y;
    const int j = blockIdx.x * 256 + t;
    zs[t] = z[b * LDIM + t];
    __syncthreads();
    float acc = b1[j];
#pragma unroll 8
    for (int l = 0; l < LDIM; ++l)
        acc = fmaf(zs[l], W1[l * HDIM + j], acc);
    float g = 0.5f * acc * (1.0f + erff(acc * 0.70710678118654752f));
    hb[(size_t)b * HDIM + j] = f2bf(g);
}

// ---------------------------------------------------------------------------
// K2 v2: v = h @ W2 + b2 via bf16 MFMA 16x16x32, no K-split, M-SPLIT in block.
// Grid: NN/16 = 2112 blocks x 256 threads (4 waves). Block owns 16 cols;
// wave w owns output rows [16w, 16w+16) (1 MFMA per 32-K step), full K=1024.
// -> 8448 waves = 32 waves/CU = 8/SIMD (was 2/SIMD in round 1: latency-hiding
// was the suspect). B-fragment loaded directly from W2 (lane(kq,nl) reads
// W2[s*32+kq*8+j][c0+nl]); the 4 waves read identical B -> L2 absorbs, HBM
// traffic stays 138 MB. Depth-2 pipeline on W2 and hb loads.
// R2 idempotent repeats for profiling; memory clobber defeats hoisting.
// ---------------------------------------------------------------------------
__global__ __launch_bounds__(256, 8) void k2_v(const float* __restrict__ W2,
                                               const float* __restrict__ b2,
                                               const unsigned short* __restrict__ hb,
                                               float* __restrict__ v) {
    const int tid  = threadIdx.x;
    const int lane = tid & 63;
    const int wave = __builtin_amdgcn_readfirstlane(tid >> 6);  // m-tile 0..3
    const int c0   = blockIdx.x * 16;
    const int kq   = lane >> 4;          // 0..3
    const int nl   = lane & 15;          // 0..15

    // B loads: row (s*32 + kq*8 + j), col (c0 + nl)
    const float* __restrict__ wp =
        W2 + (size_t)(kq * 8) * NN + (size_t)c0 + nl;
    // A loads: hb[(wave*16 + nl)*HDIM + s*32 + kq*8]
    const unsigned short* __restrict__ hp =
        hb + (size_t)(wave * 16 + nl) * HDIM + kq * 8;

    const float bias = b2[c0 + nl];
    float* __restrict__ vo = v + (size_t)c0 + nl;

#pragma unroll 1
    for (int rep = 0; rep < R2; ++rep) {
        asm volatile("" ::: "memory");   // force reloads each rep (rule #17)

        f32x4 acc = (f32x4){0.f, 0.f, 0.f, 0.f};

        auto loadW = [&](int s, float (&w)[8]) {
#pragma unroll
            for (int j = 0; j < 8; ++j)
                w[j] = wp[(size_t)(s * 32 + j) * NN];
        };
        auto loadA = [&](int s, bf16x8& a) {
            a = *(const bf16x8*)(hp + s * 32);
        };
        auto consume = [&](float (&w)[8], bf16x8& a) {
            bf16x8 bfr;
#pragma unroll
            for (int j = 0; j < 8; ++j) bfr[j] = (short)f2bf(w[j]);
            acc = __builtin_amdgcn_mfma_f32_16x16x32_bf16(a, bfr, acc, 0, 0, 0);
        };

        float  wA[8], wB[8];
        bf16x8 aA, aB;
        loadW(0, wA); loadA(0, aA);

#pragma unroll 1
        for (int sp = 0; sp < 32; sp += 2) {
            loadW(sp + 1, wB); loadA(sp + 1, aB);
            consume(wA, aA);
            const int sn = (sp + 2 < 32) ? (sp + 2) : 31;  // last pair: redundant
            loadW(sn, wA); loadA(sn, aA);
            consume(wB, aB);
        }

        // epilogue: C[m = wave*16 + kq*4 + r][n = c0 + nl]
#pragma unroll
        for (int r = 0; r < 4; ++r)
            vo[(size_t)(wave * 16 + kq * 4 + r) * NN] = acc[r] + bias;
    }
}

// ---------------------------------------------------------------------------
// K3: block = (batch b, 64-row tile). Stage v rows [i0-16, i0+80) into LDS
// (coalesced, single slice), then 64 output rows of float4 NT stores.
// R3 idempotent repeats for profiling.
// ---------------------------------------------------------------------------
__global__ __launch_bounds__(256) void k3_out(const float* __restrict__ v,
                                              float* __restrict__ out) {
    const int tid  = threadIdx.x;
    const int tile = blockIdx.x & (DDIM / RTILE - 1);
    const int b    = blockIdx.x / (DDIM / RTILE);
    const int i0 = tile * RTILE;
    const int js = (i0 >= BAND) ? (i0 - BAND) : 0;
    const int je = (i0 + RTILE + BAND <= DDIM) ? (i0 + RTILE + BAND) : DDIM;
    const int nelem = (je - js) * MNZ;                   // <= 3168

    __shared__ float ls[(RTILE + 2 * BAND) * LSTR];      // 12.75 KB

    const float* __restrict__ vb = v + (size_t)b * NN + (size_t)js * MNZ;
    const int j0 = tid * 4;

#pragma unroll 1
    for (int rep = 0; rep < R3; ++rep) {
        asm volatile("" ::: "memory");   // force re-read of v each rep

        for (int idx = tid; idx < nelem; idx += 256) {
            const int r = idx / MNZ;
            const int m = idx - r * MNZ;
            ls[r * LSTR + m] = vb[idx];
        }
        __syncthreads();

#pragma unroll 2
        for (int r = 0; r < RTILE; ++r) {
            const int i = i0 + r;
            v4f res = (v4f){0.f, 0.f, 0.f, 0.f};
            if (j0 + 3 >= i - BAND && j0 <= i + BAND) {
                const int lo_i = (i > BAND) ? (i - BAND) : 0;
#pragma unroll
                for (int c = 0; c < 4; ++c) {
                    const int j = j0 + c;
                    const int d = j - i;
                    float x = 0.0f;
                    if (d >= -BAND && d <= BAND) {
                        const int lo_j = (j > BAND) ? (j - BAND) : 0;
                        x = 0.5f * (ls[(i - js) * LSTR + (j - lo_i)] +
                                    ls[(j - js) * LSTR + (i - lo_j)]);
                        if (d == 0) x += 1.0f;
                    }
                    res[c] = x;
                }
            }
            v4f* dst = ((v4f*)out) + ((size_t)b * DDIM + i) * (DDIM / 4) + tid;
            __builtin_nontemporal_store(res, dst);
        }
        __syncthreads();   // ls rewritten next rep (same values; barrier for rigor)
    }
}

// ---------------------------------------------------------------------------
extern "C" void kernel_launch(void* const* d_in, const int* in_sizes, int n_in,
                              void* d_out, int out_size, void* d_ws, size_t ws_size,
                              hipStream_t stream) {
    const float* z  = (const float*)d_in[0];
    const float* W1 = (const float*)d_in[2];
    const float* b1 = (const float*)d_in[3];
    const float* W2 = (const float*)d_in[4];
    const float* b2 = (const float*)d_in[5];

    unsigned short* hb = (unsigned short*)d_ws;          // 64x1024 bf16 (128 KB)
    float* v = (float*)((char*)d_ws + (size_t)BATCH * HDIM * sizeof(unsigned short));
    float* out = (float*)d_out;

    k1_h  <<<dim3(4, 64), 256, 0, stream>>>(z, W1, b1, hb);
    k2_v  <<<dim3(NN / 16), 256, 0, stream>>>(W2, b2, hb, v);
    k3_out<<<dim3(BATCH * (DDIM / RTILE)), 256, 0, stream>>>(v, out);
}

// Round 3
// 429.201 us; speedup vs baseline: 4.1885x; 4.1885x over previous
//
#include <hip/hip_runtime.h>
#include <math.h>

// Problem constants
#define BATCH 64
#define LDIM  256
#define HDIM  1024
#define DDIM  1024
#define BAND  16
#define MNZ   33          // 2*BAND+1
#define NN    (DDIM*MNZ)  // 33792
#define RTILE 64          // k3 rows per block
#define LSTR  34          // k3 LDS row stride (pad 33->34)

typedef float  v4f    __attribute__((ext_vector_type(4)));
typedef float  f32x4  __attribute__((ext_vector_type(4)));
typedef short  bf16x8 __attribute__((ext_vector_type(8)));
typedef unsigned short u16x8 __attribute__((ext_vector_type(8)));

static __device__ __forceinline__ unsigned short f2bf(float x) {
    union { float f; unsigned int u; } a; a.f = x;
    unsigned int r = a.u + 0x7fffu + ((a.u >> 16) & 1u);
    return (unsigned short)(r >> 16);
}

#define GLDS16(g, l)                                                         \
    __builtin_amdgcn_global_load_lds(                                        \
        (const __attribute__((address_space(1))) void*)(g),                  \
        (__attribute__((address_space(3))) void*)(l), 16, 0, 0)

// ---------------------------------------------------------------------------
// K1: h = gelu(z @ W1 + b1), written PRE-FRAGMENTED for K2's MFMA A-operand:
//   hb_frag[(s*4 + mt)*64 + kq*16 + nl] = bf16x8 of h[mt*16+nl][s*32+kq*8 .. +8]
// Thread = (batch b, 8 consecutive cols j0..j0+8). float4 W1 loads.
// ---------------------------------------------------------------------------
__global__ __launch_bounds__(256) void k1_h(const float* __restrict__ z,
                                            const float* __restrict__ W1,
                                            const float* __restrict__ b1,
                                            unsigned short* __restrict__ hb) {
    __shared__ float zs[2][LDIM];
    const int t = threadIdx.x;
    const int b0 = blockIdx.x * 2;
    zs[0][t] = z[b0 * LDIM + t];
    zs[1][t] = z[(b0 + 1) * LDIM + t];
    __syncthreads();

    const int gid = blockIdx.x * 256 + t;
    const int b  = gid >> 7;          // batch row
    const int j8 = gid & 127;         // 8-col group
    const int j0 = j8 * 8;
    const float* __restrict__ zr = zs[t >> 7];

    float a[8];
#pragma unroll
    for (int c = 0; c < 8; ++c) a[c] = b1[j0 + c];
#pragma unroll 4
    for (int l = 0; l < LDIM; ++l) {
        const v4f w0 = *(const v4f*)&W1[(size_t)l * HDIM + j0];
        const v4f w1 = *(const v4f*)&W1[(size_t)l * HDIM + j0 + 4];
        const float zv = zr[l];
#pragma unroll
        for (int c = 0; c < 4; ++c) { a[c] = fmaf(zv, w0[c], a[c]); a[4 + c] = fmaf(zv, w1[c], a[4 + c]); }
    }
    u16x8 pk;
#pragma unroll
    for (int c = 0; c < 8; ++c) {
        const float g = 0.5f * a[c] * (1.0f + erff(a[c] * 0.70710678118654752f));
        pk[c] = f2bf(g);
    }
    // fragment address: s = j8>>2, kq = j8&3, mt = b>>4, nl = b&15
    const int s  = j8 >> 2;
    const int kq = j8 & 3;
    const int mt = b >> 4;
    const int nl = b & 15;
    ((u16x8*)hb)[(s * 4 + mt) * 64 + kq * 16 + nl] = pk;
}

// ---------------------------------------------------------------------------
// K2 v3: v = h @ W2 + b2 via bf16 MFMA 16x16x32.
// Grid: NN/64 = 528 blocks x 256 thr (4 waves). Block = 64 cols, full K=1024.
// Wave w owns cols [c0+16w, c0+16w+16), all 4 m-tiles (4 MFMA/step).
// W2 staged to LDS double-buffer [2][32][64] f32 via global_load_lds dwordx4
// (2 fat instrs/wave/step; round-2's 8 scalar gathers + reg-starved pipeline
// was the 916cy/step latency bug). A-frags: coalesced bf16x8 from hb_frag.
// ---------------------------------------------------------------------------
__global__ __launch_bounds__(256) void k2_v(const float* __restrict__ W2,
                                            const float* __restrict__ b2,
                                            const unsigned short* __restrict__ hb,
                                            float* __restrict__ v) {
    __shared__ __align__(16) float bt[2][32 * 64];   // 16 KB double buffer
    const int tid  = threadIdx.x;
    const int lane = tid & 63;
    const int w    = __builtin_amdgcn_readfirstlane(tid >> 6);
    const int c0   = blockIdx.x * 64;
    const int kq   = lane >> 4;          // 0..3
    const int nl   = lane & 15;          // 0..15

    // staging: round q, lane l -> row q*16 + 4w + (l>>4), col-chunk (l&15)*4
    const float* __restrict__ g0 =
        W2 + (size_t)(4 * w + (lane >> 4)) * NN + c0 + (lane & 15) * 4;
    // wave-uniform LDS base for round q: (q*16 + 4w)*64 floats (+ lane*16B by HW)

    f32x4 acc[4];
#pragma unroll
    for (int mt = 0; mt < 4; ++mt) acc[mt] = (f32x4){0.f, 0.f, 0.f, 0.f};

    auto stage = [&](int buf, int s) {
#pragma unroll
        for (int q = 0; q < 2; ++q)
            GLDS16(g0 + (size_t)(s * 32 + q * 16) * NN,
                   &bt[buf][(q * 16 + 4 * w) * 64]);
    };

    stage(0, 0);
    __syncthreads();

    const bf16x8* __restrict__ hbf = (const bf16x8*)hb;

#pragma unroll 1
    for (int s = 0; s < 32; ++s) {
        const int cur = s & 1;
        if (s + 1 < 32) stage(cur ^ 1, s + 1);

        bf16x8 af[4];
#pragma unroll
        for (int mt = 0; mt < 4; ++mt)
            af[mt] = hbf[(s * 4 + mt) * 64 + lane];

        float wv[8];
#pragma unroll
        for (int j = 0; j < 8; ++j)
            wv[j] = bt[cur][(kq * 8 + j) * 64 + w * 16 + nl];
        bf16x8 bfr;
#pragma unroll
        for (int j = 0; j < 8; ++j) bfr[j] = (short)f2bf(wv[j]);

#pragma unroll
        for (int mt = 0; mt < 4; ++mt)
            acc[mt] = __builtin_amdgcn_mfma_f32_16x16x32_bf16(
                af[mt], bfr, acc[mt], 0, 0, 0);

        __syncthreads();   // drains vmcnt (stage done) + orders dbuf reuse
    }

    // epilogue: C[m = mt*16 + kq*4 + r][n = c0 + w*16 + nl]
    const int col = c0 + w * 16 + nl;
    const float bias = b2[col];
    float* __restrict__ vo = v + col;
#pragma unroll
    for (int mt = 0; mt < 4; ++mt)
#pragma unroll
        for (int r = 0; r < 4; ++r)
            vo[(size_t)(mt * 16 + kq * 4 + r) * NN] = acc[mt][r] + bias;
}

// ---------------------------------------------------------------------------
// K3: block = (batch b, 64-row tile). Stage v rows [i0-16, i0+80) into LDS
// (coalesced, single slice), then 64 output rows of float4 NT stores.
// ---------------------------------------------------------------------------
__global__ __launch_bounds__(256) void k3_out(const float* __restrict__ v,
                                              float* __restrict__ out) {
    const int tid  = threadIdx.x;
    const int tile = blockIdx.x & (DDIM / RTILE - 1);
    const int b    = blockIdx.x / (DDIM / RTILE);
    const int i0 = tile * RTILE;
    const int js = (i0 >= BAND) ? (i0 - BAND) : 0;
    const int je = (i0 + RTILE + BAND <= DDIM) ? (i0 + RTILE + BAND) : DDIM;
    const int nelem = (je - js) * MNZ;                   // <= 3168

    __shared__ float ls[(RTILE + 2 * BAND) * LSTR];      // 12.75 KB

    const float* __restrict__ vb = v + (size_t)b * NN + (size_t)js * MNZ;
    for (int idx = tid; idx < nelem; idx += 256) {
        const int r = idx / MNZ;
        const int m = idx - r * MNZ;
        ls[r * LSTR + m] = vb[idx];
    }
    __syncthreads();

    const int j0 = tid * 4;
#pragma unroll 2
    for (int r = 0; r < RTILE; ++r) {
        const int i = i0 + r;
        v4f res = (v4f){0.f, 0.f, 0.f, 0.f};
        if (j0 + 3 >= i - BAND && j0 <= i + BAND) {
            const int lo_i = (i > BAND) ? (i - BAND) : 0;
#pragma unroll
            for (int c = 0; c < 4; ++c) {
                const int j = j0 + c;
                const int d = j - i;
                float x = 0.0f;
                if (d >= -BAND && d <= BAND) {
                    const int lo_j = (j > BAND) ? (j - BAND) : 0;
                    x = 0.5f * (ls[(i - js) * LSTR + (j - lo_i)] +
                                ls[(j - js) * LSTR + (i - lo_j)]);
                    if (d == 0) x += 1.0f;
                }
                res[c] = x;
            }
        }
        v4f* dst = ((v4f*)out) + ((size_t)b * DDIM + i) * (DDIM / 4) + tid;
        __builtin_nontemporal_store(res, dst);
    }
}

// ---------------------------------------------------------------------------
extern "C" void kernel_launch(void* const* d_in, const int* in_sizes, int n_in,
                              void* d_out, int out_size, void* d_ws, size_t ws_size,
                              hipStream_t stream) {
    const float* z  = (const float*)d_in[0];
    const float* W1 = (const float*)d_in[2];
    const float* b1 = (const float*)d_in[3];
    const float* W2 = (const float*)d_in[4];
    const float* b2 = (const float*)d_in[5];

    unsigned short* hb = (unsigned short*)d_ws;          // 128 KB (fragmented h)
    float* v = (float*)((char*)d_ws + (size_t)BATCH * HDIM * sizeof(unsigned short));
    float* out = (float*)d_out;

    k1_h  <<<dim3(BATCH / 2), 256, 0, stream>>>(z, W1, b1, hb);
    k2_v  <<<dim3(NN / 64), 256, 0, stream>>>(W2, b2, hb, v);
    k3_out<<<dim3(BATCH * (DDIM / RTILE)), 256, 0, stream>>>(v, out);
}